// Round 3
// baseline (308.811 us; speedup 1.0000x reference)
//
#include <hip/hip_runtime.h>
#include <hip/hip_bf16.h>

// ScoreAttention on MI355X (gfx950).
// Pipeline: gn_stats -> gn_apply -> qkv_gemm -> flash_part(x2 K-split) -> merge -> proj_gemm
// flash v3: S^T formulation, max-free softmax (clamp@60), conflict-free LDS stride 68,
// K-split=2 for 32 waves/CU occupancy, fp32 partials merged by a light kernel.

typedef __attribute__((ext_vector_type(8))) __bf16 bf16x8;
typedef __attribute__((ext_vector_type(4))) float f32x4;

#define HW 4096
#define C 256
#define NH 8
#define HD 32
#define QSCALE 0.25505654f  /* log2(e)/sqrt(32) */
#define PSTRIDE 68          /* shorts per P row: 34 dwords == 2 mod 32 -> conflict-free */

__device__ inline unsigned short f2bf(float f) {
  union { float f; unsigned int u; } v; v.f = f;
  unsigned int u = v.u;
  return (unsigned short)((u + 0x7fffu + ((u >> 16) & 1u)) >> 16);
}

__device__ inline bf16x8 load8(const unsigned short* p) {
  bf16x8 v;
  __builtin_memcpy(&v, __builtin_assume_aligned(p, 16), 16);
  return v;
}

// 8B-aligned LDS read of 8 bf16 as two b64s (ds_read2_b64-friendly)
__device__ inline bf16x8 load8_lds(const unsigned short* p) {
  uint2 a = *(const uint2*)__builtin_assume_aligned(p, 8);
  uint2 b = *(const uint2*)__builtin_assume_aligned(p + 4, 8);
  union { uint4 u; bf16x8 v; } cv;
  cv.u = make_uint4(a.x, a.y, b.x, b.y);
  return cv.v;
}

__device__ inline unsigned int fbits(float f) {
  unsigned int u; __builtin_memcpy(&u, &f, 4); return u;
}

// pack two f32 -> two bf16 in one dword (round via +0x8000, byte perm)
__device__ inline unsigned int pack_bf2(float lo, float hi) {
  return __builtin_amdgcn_perm(fbits(hi) + 0x8000u, fbits(lo) + 0x8000u, 0x07060302u);
}

// ---------------- GroupNorm stats
__global__ __launch_bounds__(256) void gn_stats(const float* __restrict__ x,
                                                float* __restrict__ stats) {
  int bg = blockIdx.x;
  const float4* p4 = (const float4*)(x + (size_t)bg * 32768);
  int t = threadIdx.x;
  float s = 0.f, ss = 0.f;
  for (int i = t; i < 8192; i += 256) {
    float4 v = p4[i];
    s  += v.x + v.y + v.z + v.w;
    ss += v.x*v.x + v.y*v.y + v.z*v.z + v.w*v.w;
  }
  for (int m = 32; m >= 1; m >>= 1) {
    s  += __shfl_down(s, m, 64);
    ss += __shfl_down(ss, m, 64);
  }
  __shared__ float red[8];
  int w = t >> 6;
  if ((t & 63) == 0) { red[w] = s; red[w + 4] = ss; }
  __syncthreads();
  if (t == 0) {
    float S  = red[0] + red[1] + red[2] + red[3];
    float SS = red[4] + red[5] + red[6] + red[7];
    float mean = S * (1.0f / 32768.0f);
    float var  = SS * (1.0f / 32768.0f) - mean * mean;
    stats[bg]      = mean;
    stats[64 + bg] = rsqrtf(var + 1e-5f);
  }
}

// ---------------- convert weights f32 -> bf16
__global__ __launch_bounds__(256) void convert_w(const float* __restrict__ wq,
                                                 const float* __restrict__ wp,
                                                 unsigned short* __restrict__ wq_b,
                                                 unsigned short* __restrict__ wp_b) {
  int base = blockIdx.x * 1024 + threadIdx.x * 4;
  #pragma unroll
  for (int k = 0; k < 4; k++) {
    int idx = base + k;
    if (idx < 196608) wq_b[idx] = f2bf(wq[idx]);
    else              wp_b[idx - 196608] = f2bf(wp[idx - 196608]);
  }
}

// ---------------- GroupNorm apply + transpose
__global__ __launch_bounds__(256) void gn_apply(const float* __restrict__ x,
                                                const float* __restrict__ stats,
                                                const float* __restrict__ gamma,
                                                const float* __restrict__ beta,
                                                unsigned short* __restrict__ h_t) {
  __shared__ float tile[64][65];
  int b = blockIdx.z, c0 = blockIdx.y * 64, s0 = blockIdx.x * 64;
  int t = threadIdx.x;
  const float* xb = x + ((size_t)b * C + c0) * HW + s0;
  #pragma unroll
  for (int k = 0; k < 16; k++) {
    int e = k * 256 + t;
    int i = e >> 6, j = e & 63;
    tile[i][j] = xb[(size_t)i * HW + j];
  }
  __syncthreads();
  unsigned short* hb = h_t + ((size_t)b * HW + s0) * C + c0;
  #pragma unroll
  for (int k = 0; k < 16; k++) {
    int e = k * 256 + t;
    int jr = e >> 6, ir = e & 63;
    int c = c0 + ir;
    int g = c >> 3;
    float mean = stats[b * 32 + g];
    float rstd = stats[64 + b * 32 + g];
    float v = (tile[ir][jr] - mean) * rstd * gamma[c] + beta[c];
    hb[(size_t)jr * C + ir] = f2bf(v);
  }
}

// ---------------- QKV GEMM
__global__ __launch_bounds__(256) void qkv_gemm(const unsigned short* __restrict__ wq_b,
                                                const unsigned short* __restrict__ h_t,
                                                const float* __restrict__ b_qkv,
                                                unsigned short* __restrict__ q_t,
                                                unsigned short* __restrict__ k_t,
                                                unsigned short* __restrict__ v_t) {
  int lane = threadIdx.x & 63, w = threadIdx.x >> 6;
  int quad = lane >> 4, l16 = lane & 15;
  int m0 = blockIdx.y * 64 + w * 16;
  int n0 = blockIdx.x * 64;
  int b  = blockIdx.z;
  f32x4 acc[4];
  #pragma unroll
  for (int nb = 0; nb < 4; nb++) acc[nb] = (f32x4){0.f, 0.f, 0.f, 0.f};

  const unsigned short* hb = h_t + (size_t)b * HW * C;
  for (int k0 = 0; k0 < 256; k0 += 32) {
    bf16x8 a = load8(wq_b + (size_t)(m0 + l16) * 256 + k0 + quad * 8);
    #pragma unroll
    for (int nb = 0; nb < 4; nb++) {
      int s = n0 + nb * 16 + l16;
      bf16x8 bb = load8(hb + (size_t)s * C + k0 + quad * 8);
      acc[nb] = __builtin_amdgcn_mfma_f32_16x16x32_bf16(a, bb, acc[nb], 0, 0, 0);
    }
  }

  int seg = m0 >> 8;
  #pragma unroll
  for (int nb = 0; nb < 4; nb++) {
    int s = n0 + nb * 16 + l16;
    #pragma unroll
    for (int r = 0; r < 4; r++) {
      int o = m0 + quad * 4 + r;
      float val = acc[nb][r] + b_qkv[o];
      if (seg == 2) {
        v_t[((size_t)b * C + (o - 512)) * HW + s] = f2bf(val);
      } else {
        int oc = o & 255, h = oc >> 5, d = oc & 31;
        unsigned short* dst = seg ? k_t : q_t;
        float sv = seg ? val : val * QSCALE;
        dst[(((size_t)b * NH + h) * HW + s) * HD + d] = f2bf(sv);
      }
    }
  }
}

// ---------------- Flash tile: 64 keys x 16 queries (one wave)
__device__ __forceinline__ void flash_tile(const unsigned short* __restrict__ K,
                                           const unsigned short* __restrict__ V,
                                           unsigned short* pw, bf16x8 b_q, int j0,
                                           int l16, int quad, float& psum, f32x4* oT) {
  const f32x4 zero = (f32x4){0.f, 0.f, 0.f, 0.f};
  f32x4 s[4];
  #pragma unroll
  for (int nb = 0; nb < 4; nb++) {
    bf16x8 a_k = load8(K + (size_t)(j0 + nb * 16 + l16) * HD + quad * 8);
    s[nb] = __builtin_amdgcn_mfma_f32_16x16x32_bf16(a_k, b_q, zero, 0, 0, 0);
  }
  #pragma unroll
  for (int nb = 0; nb < 4; nb++) {
    float p0 = __builtin_amdgcn_exp2f(fminf(s[nb][0], 60.f));
    float p1 = __builtin_amdgcn_exp2f(fminf(s[nb][1], 60.f));
    float p2 = __builtin_amdgcn_exp2f(fminf(s[nb][2], 60.f));
    float p3 = __builtin_amdgcn_exp2f(fminf(s[nb][3], 60.f));
    psum += (p0 + p1) + (p2 + p3);
    uint2 dd;
    dd.x = pack_bf2(p0, p1);
    dd.y = pack_bf2(p2, p3);
    *(uint2*)(pw + l16 * PSTRIDE + nb * 16 + quad * 4) = dd;  // 8B aligned
  }
  #pragma unroll
  for (int kb = 0; kb < 2; kb++) {
    bf16x8 bp = load8_lds(pw + l16 * PSTRIDE + kb * 32 + quad * 8);
    #pragma unroll
    for (int mb = 0; mb < 2; mb++) {
      bf16x8 a_v = load8(V + (size_t)(mb * 16 + l16) * HW + j0 + kb * 32 + quad * 8);
      oT[mb] = __builtin_amdgcn_mfma_f32_16x16x32_bf16(a_v, bp, oT[mb], 0, 0, 0);
    }
  }
}

// ---------------- Flash with K-split: grid (64 q-tiles, 16 bh, SPLIT)
// writes unnormalized fp32 O-partials + row-sums (max-free softmax => direct add)
__global__ __launch_bounds__(256, 8) void flash_part(const unsigned short* __restrict__ q_t,
                                                     const unsigned short* __restrict__ k_t,
                                                     const unsigned short* __restrict__ v_t,
                                                     float* __restrict__ po,
                                                     float* __restrict__ pl,
                                                     int jspan) {
  int lane = threadIdx.x & 63, w = threadIdx.x >> 6;
  int quad = lane >> 4, l16 = lane & 15;
  int bh = blockIdx.y, b = bh >> 3, h = bh & 7;
  int m0 = blockIdx.x * 64 + w * 16;
  int z = blockIdx.z;

  __shared__ __align__(16) unsigned short pbuf[8][16 * PSTRIDE];
  unsigned short* pwA = &pbuf[w * 2][0];
  unsigned short* pwB = &pbuf[w * 2 + 1][0];

  const unsigned short* Q = q_t + (size_t)bh * HW * HD;
  const unsigned short* K = k_t + (size_t)bh * HW * HD;
  const unsigned short* V = v_t + ((size_t)b * C + h * HD) * HW;

  bf16x8 b_q = load8(Q + (size_t)(m0 + l16) * HD + quad * 8);

  float psum = 0.f;
  f32x4 oT[2];
  oT[0] = (f32x4){0.f, 0.f, 0.f, 0.f};
  oT[1] = (f32x4){0.f, 0.f, 0.f, 0.f};

  int jbase = z * jspan;
  for (int j0 = jbase; j0 < jbase + jspan; j0 += 128) {
    flash_tile(K, V, pwA, b_q, j0,      l16, quad, psum, oT);
    flash_tile(K, V, pwB, b_q, j0 + 64, l16, quad, psum, oT);
  }

  psum += __shfl_xor(psum, 16, 64);
  psum += __shfl_xor(psum, 32, 64);

  int s = m0 + l16;
  float* prow = po + (((size_t)z * 16 + bh) * HW + s) * 32;
  #pragma unroll
  for (int mb = 0; mb < 2; mb++)
    *(f32x4*)(prow + mb * 16 + quad * 4) = oT[mb];
  if (lane < 16)
    pl[((size_t)z * 16 + bh) * HW + s] = psum;
}

// ---------------- merge partials -> ao_t[b][s][c] bf16
__global__ __launch_bounds__(256) void merge_parts(const float* __restrict__ po,
                                                   const float* __restrict__ pl,
                                                   unsigned short* __restrict__ ao_t) {
  int g = blockIdx.x * 256 + threadIdx.x;   // [0, 16*4096*8)
  int d4 = g & 7, s = (g >> 3) & 4095, bh = g >> 15;
  const float4* p4 = (const float4*)po;
  float4 a = p4[g];
  float4 c = p4[g + (16 * HW * 32 / 4)];
  float l = pl[(size_t)bh * HW + s] + pl[(size_t)(16 + bh) * HW + s];
  float inv = 1.0f / l;
  int b = bh >> 3, h = bh & 7;
  uint2 dd;
  dd.x = pack_bf2((a.x + c.x) * inv, (a.y + c.y) * inv);
  dd.y = pack_bf2((a.z + c.z) * inv, (a.w + c.w) * inv);
  *(uint2*)(ao_t + ((size_t)b * HW + s) * C + h * HD + d4 * 4) = dd;
}

// ---------------- direct (no-split) fallback flash
__global__ __launch_bounds__(256) void flash_direct(const unsigned short* __restrict__ q_t,
                                                    const unsigned short* __restrict__ k_t,
                                                    const unsigned short* __restrict__ v_t,
                                                    unsigned short* __restrict__ ao_t) {
  int lane = threadIdx.x & 63, w = threadIdx.x >> 6;
  int quad = lane >> 4, l16 = lane & 15;
  int bh = blockIdx.y, b = bh >> 3, h = bh & 7;
  int m0 = blockIdx.x * 64 + w * 16;

  __shared__ __align__(16) unsigned short pbuf[8][16 * PSTRIDE];
  unsigned short* pwA = &pbuf[w * 2][0];
  unsigned short* pwB = &pbuf[w * 2 + 1][0];

  const unsigned short* Q = q_t + (size_t)bh * HW * HD;
  const unsigned short* K = k_t + (size_t)bh * HW * HD;
  const unsigned short* V = v_t + ((size_t)b * C + h * HD) * HW;

  bf16x8 b_q = load8(Q + (size_t)(m0 + l16) * HD + quad * 8);

  float psum = 0.f;
  f32x4 oT[2];
  oT[0] = (f32x4){0.f, 0.f, 0.f, 0.f};
  oT[1] = (f32x4){0.f, 0.f, 0.f, 0.f};

  for (int j0 = 0; j0 < HW; j0 += 128) {
    flash_tile(K, V, pwA, b_q, j0,      l16, quad, psum, oT);
    flash_tile(K, V, pwB, b_q, j0 + 64, l16, quad, psum, oT);
  }

  psum += __shfl_xor(psum, 16, 64);
  psum += __shfl_xor(psum, 32, 64);
  float inv = 1.0f / psum;

  unsigned short* orow = ao_t + ((size_t)b * HW + m0 + l16) * C + h * HD;
  #pragma unroll
  for (int mb = 0; mb < 2; mb++) {
    uint2 dd;
    dd.x = pack_bf2(oT[mb][0] * inv, oT[mb][1] * inv);
    dd.y = pack_bf2(oT[mb][2] * inv, oT[mb][3] * inv);
    *(uint2*)(orow + mb * 16 + quad * 4) = dd;
  }
}

// ---------------- Proj GEMM + bias + residual
__global__ __launch_bounds__(256) void proj_gemm(const unsigned short* __restrict__ wp_b,
                                                 const unsigned short* __restrict__ ao_t,
                                                 const float* __restrict__ b_proj,
                                                 const float* __restrict__ x,
                                                 float* __restrict__ out) {
  int lane = threadIdx.x & 63, w = threadIdx.x >> 6;
  int quad = lane >> 4, l16 = lane & 15;
  int m0 = blockIdx.y * 64 + w * 16;
  int n0 = blockIdx.x * 64;
  int b  = blockIdx.z;
  f32x4 acc[4];
  #pragma unroll
  for (int nb = 0; nb < 4; nb++) acc[nb] = (f32x4){0.f, 0.f, 0.f, 0.f};

  const unsigned short* ab = ao_t + (size_t)b * HW * C;
  for (int k0 = 0; k0 < 256; k0 += 32) {
    bf16x8 a = load8(wp_b + (size_t)(m0 + l16) * 256 + k0 + quad * 8);
    #pragma unroll
    for (int nb = 0; nb < 4; nb++) {
      int s = n0 + nb * 16 + l16;
      bf16x8 bb = load8(ab + (size_t)s * C + k0 + quad * 8);
      acc[nb] = __builtin_amdgcn_mfma_f32_16x16x32_bf16(a, bb, acc[nb], 0, 0, 0);
    }
  }
  #pragma unroll
  for (int nb = 0; nb < 4; nb++) {
    int s = n0 + nb * 16 + l16;
    #pragma unroll
    for (int r = 0; r < 4; r++) {
      int o = m0 + quad * 4 + r;
      size_t idx = ((size_t)b * C + o) * HW + s;
      out[idx] = acc[nb][r] + b_proj[o] + x[idx];
    }
  }
}

extern "C" void kernel_launch(void* const* d_in, const int* in_sizes, int n_in,
                              void* d_out, int out_size, void* d_ws, size_t ws_size,
                              hipStream_t stream) {
  const float* x      = (const float*)d_in[0];
  const float* w_qkv  = (const float*)d_in[1];
  const float* b_qkv  = (const float*)d_in[2];
  const float* w_proj = (const float*)d_in[3];
  const float* b_proj = (const float*)d_in[4];
  const float* gamma  = (const float*)d_in[5];
  const float* beta   = (const float*)d_in[6];
  float* out = (float*)d_out;

  char* ws = (char*)d_ws;
  float*          stats = (float*)ws;                                   // 512 B
  unsigned short* wq_b  = (unsigned short*)(ws + 512);                  // 384 KB
  unsigned short* wp_b  = (unsigned short*)(ws + 512 + 393216);         // 128 KB
  unsigned short* h_t   = (unsigned short*)(ws + 524800);               // 4 MB [b][s][c]
  unsigned short* q_t   = (unsigned short*)(ws + 4719104);              // 4 MB [bh][s][d]
  unsigned short* k_t   = (unsigned short*)(ws + 8913408);              // 4 MB [bh][s][d]
  unsigned short* v_t   = (unsigned short*)(ws + 13107712);             // 4 MB [b][c][s]
  unsigned short* ao_t  = (unsigned short*)(ws + 17302016);             // 4 MB [b][s][c]
  float*          po    = (float*)(ws + 21496320);                      // 16 MB (2 splits)
  float*          pl    = (float*)(ws + 21496320 + 16777216);           // 512 KB
  size_t need_split = 21496320 + 16777216 + 524288;

  gn_stats<<<64, 256, 0, stream>>>(x, stats);
  convert_w<<<256, 256, 0, stream>>>(w_qkv, w_proj, wq_b, wp_b);
  gn_apply<<<dim3(64, 4, 2), 256, 0, stream>>>(x, stats, gamma, beta, h_t);
  qkv_gemm<<<dim3(64, 12, 2), 256, 0, stream>>>(wq_b, h_t, b_qkv, q_t, k_t, v_t);
  if (ws_size >= need_split) {
    flash_part<<<dim3(64, 16, 2), 256, 0, stream>>>(q_t, k_t, v_t, po, pl, HW / 2);
    merge_parts<<<2048, 256, 0, stream>>>(po, pl, ao_t);
  } else {
    flash_direct<<<dim3(64, 16), 256, 0, stream>>>(q_t, k_t, v_t, ao_t);
  }
  proj_gemm<<<dim3(64, 4, 2), 256, 0, stream>>>(wp_b, ao_t, b_proj, x, out);
}

// Round 4
// 227.495 us; speedup vs baseline: 1.3574x; 1.3574x over previous
//
#include <hip/hip_runtime.h>
#include <hip/hip_bf16.h>

// ScoreAttention on MI355X (gfx950).
// Pipeline: gn_stats -> gn_apply -> qkv_gemm -> flash_part(x2 K-split, 32x32 MFMA) -> merge -> proj_gemm
// flash v4: 32x32x16 MFMAs, wave tile = 32 queries x 128 keys, S^T formulation,
// max-free exp2 softmax (no clamp; scores bounded), P^T via LDS [query][key] stride-136.

typedef __attribute__((ext_vector_type(8))) __bf16 bf16x8;
typedef __attribute__((ext_vector_type(4))) float f32x4;
typedef __attribute__((ext_vector_type(16))) float f32x16;

#define HW 4096
#define C 256
#define NH 8
#define HD 32
#define QSCALE 0.25505654f  /* log2(e)/sqrt(32) */
#define PST 136             /* shorts per P row: 68 dwords == 4 mod 32, 16B-aligned rows */

__device__ inline unsigned short f2bf(float f) {
  union { float f; unsigned int u; } v; v.f = f;
  unsigned int u = v.u;
  return (unsigned short)((u + 0x7fffu + ((u >> 16) & 1u)) >> 16);
}

__device__ inline bf16x8 load8(const unsigned short* p) {
  bf16x8 v;
  __builtin_memcpy(&v, __builtin_assume_aligned(p, 16), 16);
  return v;
}

__device__ inline unsigned int fbits(float f) {
  unsigned int u; __builtin_memcpy(&u, &f, 4); return u;
}

// pack two f32 -> two bf16 in one dword (round via +0x8000, byte perm)
__device__ inline unsigned int pack_bf2(float lo, float hi) {
  return __builtin_amdgcn_perm(fbits(hi) + 0x8000u, fbits(lo) + 0x8000u, 0x07060302u);
}

// ---------------- GroupNorm stats
__global__ __launch_bounds__(256) void gn_stats(const float* __restrict__ x,
                                                float* __restrict__ stats) {
  int bg = blockIdx.x;
  const float4* p4 = (const float4*)(x + (size_t)bg * 32768);
  int t = threadIdx.x;
  float s = 0.f, ss = 0.f;
  for (int i = t; i < 8192; i += 256) {
    float4 v = p4[i];
    s  += v.x + v.y + v.z + v.w;
    ss += v.x*v.x + v.y*v.y + v.z*v.z + v.w*v.w;
  }
  for (int m = 32; m >= 1; m >>= 1) {
    s  += __shfl_down(s, m, 64);
    ss += __shfl_down(ss, m, 64);
  }
  __shared__ float red[8];
  int w = t >> 6;
  if ((t & 63) == 0) { red[w] = s; red[w + 4] = ss; }
  __syncthreads();
  if (t == 0) {
    float S  = red[0] + red[1] + red[2] + red[3];
    float SS = red[4] + red[5] + red[6] + red[7];
    float mean = S * (1.0f / 32768.0f);
    float var  = SS * (1.0f / 32768.0f) - mean * mean;
    stats[bg]      = mean;
    stats[64 + bg] = rsqrtf(var + 1e-5f);
  }
}

// ---------------- convert weights f32 -> bf16
__global__ __launch_bounds__(256) void convert_w(const float* __restrict__ wq,
                                                 const float* __restrict__ wp,
                                                 unsigned short* __restrict__ wq_b,
                                                 unsigned short* __restrict__ wp_b) {
  int base = blockIdx.x * 1024 + threadIdx.x * 4;
  #pragma unroll
  for (int k = 0; k < 4; k++) {
    int idx = base + k;
    if (idx < 196608) wq_b[idx] = f2bf(wq[idx]);
    else              wp_b[idx - 196608] = f2bf(wp[idx - 196608]);
  }
}

// ---------------- GroupNorm apply + transpose
__global__ __launch_bounds__(256) void gn_apply(const float* __restrict__ x,
                                                const float* __restrict__ stats,
                                                const float* __restrict__ gamma,
                                                const float* __restrict__ beta,
                                                unsigned short* __restrict__ h_t) {
  __shared__ float tile[64][65];
  int b = blockIdx.z, c0 = blockIdx.y * 64, s0 = blockIdx.x * 64;
  int t = threadIdx.x;
  const float* xb = x + ((size_t)b * C + c0) * HW + s0;
  #pragma unroll
  for (int k = 0; k < 16; k++) {
    int e = k * 256 + t;
    int i = e >> 6, j = e & 63;
    tile[i][j] = xb[(size_t)i * HW + j];
  }
  __syncthreads();
  unsigned short* hb = h_t + ((size_t)b * HW + s0) * C + c0;
  #pragma unroll
  for (int k = 0; k < 16; k++) {
    int e = k * 256 + t;
    int jr = e >> 6, ir = e & 63;
    int c = c0 + ir;
    int g = c >> 3;
    float mean = stats[b * 32 + g];
    float rstd = stats[64 + b * 32 + g];
    float v = (tile[ir][jr] - mean) * rstd * gamma[c] + beta[c];
    hb[(size_t)jr * C + ir] = f2bf(v);
  }
}

// ---------------- QKV GEMM
__global__ __launch_bounds__(256) void qkv_gemm(const unsigned short* __restrict__ wq_b,
                                                const unsigned short* __restrict__ h_t,
                                                const float* __restrict__ b_qkv,
                                                unsigned short* __restrict__ q_t,
                                                unsigned short* __restrict__ k_t,
                                                unsigned short* __restrict__ v_t) {
  int lane = threadIdx.x & 63, w = threadIdx.x >> 6;
  int quad = lane >> 4, l16 = lane & 15;
  int m0 = blockIdx.y * 64 + w * 16;
  int n0 = blockIdx.x * 64;
  int b  = blockIdx.z;
  f32x4 acc[4];
  #pragma unroll
  for (int nb = 0; nb < 4; nb++) acc[nb] = (f32x4){0.f, 0.f, 0.f, 0.f};

  const unsigned short* hb = h_t + (size_t)b * HW * C;
  for (int k0 = 0; k0 < 256; k0 += 32) {
    bf16x8 a = load8(wq_b + (size_t)(m0 + l16) * 256 + k0 + quad * 8);
    #pragma unroll
    for (int nb = 0; nb < 4; nb++) {
      int s = n0 + nb * 16 + l16;
      bf16x8 bb = load8(hb + (size_t)s * C + k0 + quad * 8);
      acc[nb] = __builtin_amdgcn_mfma_f32_16x16x32_bf16(a, bb, acc[nb], 0, 0, 0);
    }
  }

  int seg = m0 >> 8;
  #pragma unroll
  for (int nb = 0; nb < 4; nb++) {
    int s = n0 + nb * 16 + l16;
    #pragma unroll
    for (int r = 0; r < 4; r++) {
      int o = m0 + quad * 4 + r;
      float val = acc[nb][r] + b_qkv[o];
      if (seg == 2) {
        v_t[((size_t)b * C + (o - 512)) * HW + s] = f2bf(val);
      } else {
        int oc = o & 255, h = oc >> 5, d = oc & 31;
        unsigned short* dst = seg ? k_t : q_t;
        float sv = seg ? val : val * QSCALE;
        dst[(((size_t)b * NH + h) * HW + s) * HD + d] = f2bf(sv);
      }
    }
  }
}

// ---------------- Flash v4: 32x32x16 MFMA, wave = 32 queries x 128 keys per iter
// grid (32 q-tiles, 16 bh, 2 splits), 4 waves/block
__global__ __launch_bounds__(256) void flash_part(const unsigned short* __restrict__ q_t,
                                                  const unsigned short* __restrict__ k_t,
                                                  const unsigned short* __restrict__ v_t,
                                                  float* __restrict__ po,
                                                  float* __restrict__ pl,
                                                  int jspan) {
  int lane = threadIdx.x & 63, w = threadIdx.x >> 6;
  int n = lane & 31, hi = lane >> 5;
  int bh = blockIdx.y, b = bh >> 3, h = bh & 7;
  int m0 = blockIdx.x * 128 + w * 32;
  int z = blockIdx.z;

  __shared__ __align__(16) unsigned short pbuf[4][32 * PST];
  unsigned short* prow = &pbuf[w][0] + n * PST;

  const unsigned short* Q = q_t + (size_t)bh * HW * HD;
  const unsigned short* K = k_t + (size_t)bh * HW * HD;
  const unsigned short* V = v_t + ((size_t)b * C + h * HD) * HW + (size_t)n * HW;

  // B-operand Q fragments: lane holds query n, k = dhalf*16 + hi*8 + j
  bf16x8 qf0 = load8(Q + (size_t)(m0 + n) * HD + hi * 8);
  bf16x8 qf1 = load8(Q + (size_t)(m0 + n) * HD + 16 + hi * 8);

  float psum = 0.f;
  f32x16 oT = (f32x16){0.f,0.f,0.f,0.f,0.f,0.f,0.f,0.f,0.f,0.f,0.f,0.f,0.f,0.f,0.f,0.f};
  const f32x16 zero16 = (f32x16){0.f,0.f,0.f,0.f,0.f,0.f,0.f,0.f,0.f,0.f,0.f,0.f,0.f,0.f,0.f,0.f};

  int jbase = z * jspan;
  for (int j0 = jbase; j0 < jbase + jspan; j0 += 128) {
    // ---- QK^T -> exp2 -> pack to LDS, per 32-key block
    #pragma unroll
    for (int kb = 0; kb < 4; kb++) {
      // A-operand K fragments: lane holds key (kb*32+n), k = dhalf*16 + hi*8 + j
      const unsigned short* kp = K + (size_t)(j0 + kb * 32 + n) * HD + hi * 8;
      bf16x8 kf0 = load8(kp);
      bf16x8 kf1 = load8(kp + 16);
      f32x16 S = __builtin_amdgcn_mfma_f32_32x32x16_bf16(kf1, qf1, zero16, 0, 0, 0);
      S = __builtin_amdgcn_mfma_f32_32x32x16_bf16(kf0, qf0, S, 0, 0, 0);
      // lane holds: query col=n, keys r_loc = (reg&3) + 8*(reg>>2) + 4*hi
      float p[16];
      #pragma unroll
      for (int r = 0; r < 16; r++) {
        p[r] = __builtin_amdgcn_exp2f(S[r]);
        psum += p[r];
      }
      #pragma unroll
      for (int g = 0; g < 4; g++) {
        uint2 dd;
        dd.x = pack_bf2(p[4 * g], p[4 * g + 1]);
        dd.y = pack_bf2(p[4 * g + 2], p[4 * g + 3]);
        // P[query n][key kb*32 + g*8 + 4*hi + {0..3}]
        *(uint2*)(prow + kb * 32 + g * 8 + hi * 4) = dd;
      }
    }
    __asm__ __volatile__("" ::: "memory");  // keep LDS writes before reads
    // ---- PV: O^T[d][q] += V^T[d][k] * P^T[k][q], k in 8 blocks of 16
    #pragma unroll
    for (int t = 0; t < 8; t++) {
      bf16x8 vf = load8(V + j0 + t * 16 + hi * 8);      // A: m=d(n), k=keys
      bf16x8 pf = load8(prow + t * 16 + hi * 8);        // B: n=query, k=keys
      oT = __builtin_amdgcn_mfma_f32_32x32x16_bf16(vf, pf, oT, 0, 0, 0);
    }
  }

  // l[query]: lane n holds half the keys, partner lane n^32 the other half
  psum += __shfl_xor(psum, 32, 64);

  // O^T: col=query n, row=d = (reg&3)+8*(reg>>2)+4*hi
  float* pr = po + (((size_t)z * 16 + bh) * HW + (m0 + n)) * 32;
  #pragma unroll
  for (int g = 0; g < 4; g++) {
    f32x4 v4 = (f32x4){oT[4 * g], oT[4 * g + 1], oT[4 * g + 2], oT[4 * g + 3]};
    *(f32x4*)(pr + g * 8 + hi * 4) = v4;
  }
  if (lane < 32)
    pl[((size_t)z * 16 + bh) * HW + m0 + n] = psum;
}

// ---------------- merge partials -> ao_t[b][s][c] bf16
__global__ __launch_bounds__(256) void merge_parts(const float* __restrict__ po,
                                                   const float* __restrict__ pl,
                                                   unsigned short* __restrict__ ao_t) {
  int g = blockIdx.x * 256 + threadIdx.x;   // [0, 16*4096*8)
  int d4 = g & 7, s = (g >> 3) & 4095, bh = g >> 15;
  const float4* p4 = (const float4*)po;
  float4 a = p4[g];
  float4 c = p4[g + (16 * HW * 32 / 4)];
  float l = pl[(size_t)bh * HW + s] + pl[(size_t)(16 + bh) * HW + s];
  float inv = 1.0f / l;
  int b = bh >> 3, h = bh & 7;
  uint2 dd;
  dd.x = pack_bf2((a.x + c.x) * inv, (a.y + c.y) * inv);
  dd.y = pack_bf2((a.z + c.z) * inv, (a.w + c.w) * inv);
  *(uint2*)(ao_t + ((size_t)b * HW + s) * C + h * HD + d4 * 4) = dd;
}

// ---------------- Proj GEMM + bias + residual
__global__ __launch_bounds__(256) void proj_gemm(const unsigned short* __restrict__ wp_b,
                                                 const unsigned short* __restrict__ ao_t,
                                                 const float* __restrict__ b_proj,
                                                 const float* __restrict__ x,
                                                 float* __restrict__ out) {
  int lane = threadIdx.x & 63, w = threadIdx.x >> 6;
  int quad = lane >> 4, l16 = lane & 15;
  int m0 = blockIdx.y * 64 + w * 16;
  int n0 = blockIdx.x * 64;
  int b  = blockIdx.z;
  f32x4 acc[4];
  #pragma unroll
  for (int nb = 0; nb < 4; nb++) acc[nb] = (f32x4){0.f, 0.f, 0.f, 0.f};

  const unsigned short* ab = ao_t + (size_t)b * HW * C;
  for (int k0 = 0; k0 < 256; k0 += 32) {
    bf16x8 a = load8(wp_b + (size_t)(m0 + l16) * 256 + k0 + quad * 8);
    #pragma unroll
    for (int nb = 0; nb < 4; nb++) {
      int s = n0 + nb * 16 + l16;
      bf16x8 bb = load8(ab + (size_t)s * C + k0 + quad * 8);
      acc[nb] = __builtin_amdgcn_mfma_f32_16x16x32_bf16(a, bb, acc[nb], 0, 0, 0);
    }
  }
  #pragma unroll
  for (int nb = 0; nb < 4; nb++) {
    int s = n0 + nb * 16 + l16;
    #pragma unroll
    for (int r = 0; r < 4; r++) {
      int o = m0 + quad * 4 + r;
      size_t idx = ((size_t)b * C + o) * HW + s;
      out[idx] = acc[nb][r] + b_proj[o] + x[idx];
    }
  }
}

extern "C" void kernel_launch(void* const* d_in, const int* in_sizes, int n_in,
                              void* d_out, int out_size, void* d_ws, size_t ws_size,
                              hipStream_t stream) {
  const float* x      = (const float*)d_in[0];
  const float* w_qkv  = (const float*)d_in[1];
  const float* b_qkv  = (const float*)d_in[2];
  const float* w_proj = (const float*)d_in[3];
  const float* b_proj = (const float*)d_in[4];
  const float* gamma  = (const float*)d_in[5];
  const float* beta   = (const float*)d_in[6];
  float* out = (float*)d_out;

  char* ws = (char*)d_ws;
  float*          stats = (float*)ws;                                   // 512 B
  unsigned short* wq_b  = (unsigned short*)(ws + 512);                  // 384 KB
  unsigned short* wp_b  = (unsigned short*)(ws + 512 + 393216);         // 128 KB
  unsigned short* h_t   = (unsigned short*)(ws + 524800);               // 4 MB [b][s][c]
  unsigned short* q_t   = (unsigned short*)(ws + 4719104);              // 4 MB [bh][s][d]
  unsigned short* k_t   = (unsigned short*)(ws + 8913408);              // 4 MB [bh][s][d]
  unsigned short* v_t   = (unsigned short*)(ws + 13107712);             // 4 MB [b][c][s]
  unsigned short* ao_t  = (unsigned short*)(ws + 17302016);             // 4 MB [b][s][c]
  float*          po    = (float*)(ws + 21496320);                      // 16 MB (2 splits)
  float*          pl    = (float*)(ws + 21496320 + 16777216);           // 512 KB

  gn_stats<<<64, 256, 0, stream>>>(x, stats);
  convert_w<<<256, 256, 0, stream>>>(w_qkv, w_proj, wq_b, wp_b);
  gn_apply<<<dim3(64, 4, 2), 256, 0, stream>>>(x, stats, gamma, beta, h_t);
  qkv_gemm<<<dim3(64, 12, 2), 256, 0, stream>>>(wq_b, h_t, b_qkv, q_t, k_t, v_t);
  flash_part<<<dim3(32, 16, 2), 256, 0, stream>>>(q_t, k_t, v_t, po, pl, HW / 2);
  merge_parts<<<2048, 256, 0, stream>>>(po, pl, ao_t);
  proj_gemm<<<dim3(64, 4, 2), 256, 0, stream>>>(wp_b, ao_t, b_proj, x, out);
}

// Round 5
// 223.749 us; speedup vs baseline: 1.3802x; 1.0167x over previous
//
#include <hip/hip_runtime.h>
#include <hip/hip_bf16.h>

// ScoreAttention on MI355X (gfx950).
// Pipeline: gn_stats+convert_w -> gn_apply -> qkv_gemm -> flash_part(x2 K-split) -> merge -> proj_gemm
// flash v5: 32x32x16 MFMAs, wave tile = 32 queries x 128 keys, S^T formulation,
// max-free exp2 softmax, P via LDS [query][key] stride-136, dependency-ordered
// loop body (K loads -> V loads -> QK -> exp/pack -> DS -> PV), no asm barrier.

typedef __attribute__((ext_vector_type(8))) __bf16 bf16x8;
typedef __attribute__((ext_vector_type(4))) float f32x4;
typedef __attribute__((ext_vector_type(16))) float f32x16;

#define HW 4096
#define C 256
#define NH 8
#define HD 32
#define QSCALE 0.25505654f  /* log2(e)/sqrt(32) */
#define PST 136             /* shorts per P row: 68 dwords == 4 mod 32, balanced banks */

__device__ inline unsigned short f2bf(float f) {
  union { float f; unsigned int u; } v; v.f = f;
  unsigned int u = v.u;
  return (unsigned short)((u + 0x7fffu + ((u >> 16) & 1u)) >> 16);
}

__device__ inline bf16x8 load8(const unsigned short* p) {
  bf16x8 v;
  __builtin_memcpy(&v, __builtin_assume_aligned(p, 16), 16);
  return v;
}

__device__ inline unsigned int fbits(float f) {
  unsigned int u; __builtin_memcpy(&u, &f, 4); return u;
}

// pack two f32 -> two bf16 in one dword (round via +0x8000, byte perm)
__device__ inline unsigned int pack_bf2(float lo, float hi) {
  return __builtin_amdgcn_perm(fbits(hi) + 0x8000u, fbits(lo) + 0x8000u, 0x07060302u);
}

// ---------------- GroupNorm stats (blocks 0..63) + weight conversion (blocks 64..319)
__global__ __launch_bounds__(256) void gn_stats_conv(const float* __restrict__ x,
                                                     float* __restrict__ stats,
                                                     const float* __restrict__ wq,
                                                     const float* __restrict__ wp,
                                                     unsigned short* __restrict__ wq_b,
                                                     unsigned short* __restrict__ wp_b) {
  if (blockIdx.x >= 64) {
    int base = (blockIdx.x - 64) * 1024 + threadIdx.x * 4;
    #pragma unroll
    for (int k = 0; k < 4; k++) {
      int idx = base + k;
      if (idx < 196608) wq_b[idx] = f2bf(wq[idx]);
      else              wp_b[idx - 196608] = f2bf(wp[idx - 196608]);
    }
    return;
  }
  int bg = blockIdx.x;
  const float4* p4 = (const float4*)(x + (size_t)bg * 32768);
  int t = threadIdx.x;
  float s = 0.f, ss = 0.f;
  for (int i = t; i < 8192; i += 256) {
    float4 v = p4[i];
    s  += v.x + v.y + v.z + v.w;
    ss += v.x*v.x + v.y*v.y + v.z*v.z + v.w*v.w;
  }
  for (int m = 32; m >= 1; m >>= 1) {
    s  += __shfl_down(s, m, 64);
    ss += __shfl_down(ss, m, 64);
  }
  __shared__ float red[8];
  int w = t >> 6;
  if ((t & 63) == 0) { red[w] = s; red[w + 4] = ss; }
  __syncthreads();
  if (t == 0) {
    float S  = red[0] + red[1] + red[2] + red[3];
    float SS = red[4] + red[5] + red[6] + red[7];
    float mean = S * (1.0f / 32768.0f);
    float var  = SS * (1.0f / 32768.0f) - mean * mean;
    stats[bg]      = mean;
    stats[64 + bg] = rsqrtf(var + 1e-5f);
  }
}

// ---------------- GroupNorm apply + transpose
__global__ __launch_bounds__(256) void gn_apply(const float* __restrict__ x,
                                                const float* __restrict__ stats,
                                                const float* __restrict__ gamma,
                                                const float* __restrict__ beta,
                                                unsigned short* __restrict__ h_t) {
  __shared__ float tile[64][65];
  int b = blockIdx.z, c0 = blockIdx.y * 64, s0 = blockIdx.x * 64;
  int t = threadIdx.x;
  const float* xb = x + ((size_t)b * C + c0) * HW + s0;
  #pragma unroll
  for (int k = 0; k < 16; k++) {
    int e = k * 256 + t;
    int i = e >> 6, j = e & 63;
    tile[i][j] = xb[(size_t)i * HW + j];
  }
  __syncthreads();
  unsigned short* hb = h_t + ((size_t)b * HW + s0) * C + c0;
  #pragma unroll
  for (int k = 0; k < 16; k++) {
    int e = k * 256 + t;
    int jr = e >> 6, ir = e & 63;
    int c = c0 + ir;
    int g = c >> 3;
    float mean = stats[b * 32 + g];
    float rstd = stats[64 + b * 32 + g];
    float v = (tile[ir][jr] - mean) * rstd * gamma[c] + beta[c];
    hb[(size_t)jr * C + ir] = f2bf(v);
  }
}

// ---------------- QKV GEMM
__global__ __launch_bounds__(256) void qkv_gemm(const unsigned short* __restrict__ wq_b,
                                                const unsigned short* __restrict__ h_t,
                                                const float* __restrict__ b_qkv,
                                                unsigned short* __restrict__ q_t,
                                                unsigned short* __restrict__ k_t,
                                                unsigned short* __restrict__ v_t) {
  int lane = threadIdx.x & 63, w = threadIdx.x >> 6;
  int quad = lane >> 4, l16 = lane & 15;
  int m0 = blockIdx.y * 64 + w * 16;
  int n0 = blockIdx.x * 64;
  int b  = blockIdx.z;
  f32x4 acc[4];
  #pragma unroll
  for (int nb = 0; nb < 4; nb++) acc[nb] = (f32x4){0.f, 0.f, 0.f, 0.f};

  const unsigned short* hb = h_t + (size_t)b * HW * C;
  for (int k0 = 0; k0 < 256; k0 += 32) {
    bf16x8 a = load8(wq_b + (size_t)(m0 + l16) * 256 + k0 + quad * 8);
    #pragma unroll
    for (int nb = 0; nb < 4; nb++) {
      int s = n0 + nb * 16 + l16;
      bf16x8 bb = load8(hb + (size_t)s * C + k0 + quad * 8);
      acc[nb] = __builtin_amdgcn_mfma_f32_16x16x32_bf16(a, bb, acc[nb], 0, 0, 0);
    }
  }

  int seg = m0 >> 8;
  #pragma unroll
  for (int nb = 0; nb < 4; nb++) {
    int s = n0 + nb * 16 + l16;
    #pragma unroll
    for (int r = 0; r < 4; r++) {
      int o = m0 + quad * 4 + r;
      float val = acc[nb][r] + b_qkv[o];
      if (seg == 2) {
        v_t[((size_t)b * C + (o - 512)) * HW + s] = f2bf(val);
      } else {
        int oc = o & 255, h = oc >> 5, d = oc & 31;
        unsigned short* dst = seg ? k_t : q_t;
        float sv = seg ? val : val * QSCALE;
        dst[(((size_t)b * NH + h) * HW + s) * HD + d] = f2bf(sv);
      }
    }
  }
}

// ---------------- Flash v5: 32x32x16 MFMA, wave = 32 queries x 128 keys per iter
// grid (32 q-tiles, 16 bh, 2 splits), 4 waves/block
__global__ __launch_bounds__(256) void flash_part(const unsigned short* __restrict__ q_t,
                                                  const unsigned short* __restrict__ k_t,
                                                  const unsigned short* __restrict__ v_t,
                                                  float* __restrict__ po,
                                                  float* __restrict__ pl,
                                                  int jspan) {
  int lane = threadIdx.x & 63, w = threadIdx.x >> 6;
  int n = lane & 31, hi = lane >> 5;
  int bh = blockIdx.y, b = bh >> 3, h = bh & 7;
  int m0 = blockIdx.x * 128 + w * 32;
  int z = blockIdx.z;

  __shared__ __align__(16) unsigned short pbuf[4][32 * PST];
  unsigned short* prow = &pbuf[w][0] + n * PST;

  const unsigned short* Q = q_t + (size_t)bh * HW * HD;
  const unsigned short* K = k_t + (size_t)bh * HW * HD;
  const unsigned short* V = v_t + ((size_t)b * C + h * HD) * HW + (size_t)n * HW;

  // B-operand Q fragments: lane holds query n, k = dhalf*16 + hi*8 + j
  bf16x8 qf0 = load8(Q + (size_t)(m0 + n) * HD + hi * 8);
  bf16x8 qf1 = load8(Q + (size_t)(m0 + n) * HD + 16 + hi * 8);

  float psum = 0.f;
  f32x16 oT = (f32x16){0.f,0.f,0.f,0.f,0.f,0.f,0.f,0.f,0.f,0.f,0.f,0.f,0.f,0.f,0.f,0.f};
  const f32x16 zero16 = (f32x16){0.f,0.f,0.f,0.f,0.f,0.f,0.f,0.f,0.f,0.f,0.f,0.f,0.f,0.f,0.f,0.f};

  int jbase = z * jspan;
  for (int j0 = jbase; j0 < jbase + jspan; j0 += 128) {
    // ---- issue all K loads (needed first)
    bf16x8 kf0[4], kf1[4];
    #pragma unroll
    for (int kb = 0; kb < 4; kb++) {
      const unsigned short* kp = K + (size_t)(j0 + kb * 32 + n) * HD + hi * 8;
      kf0[kb] = load8(kp);
      kf1[kb] = load8(kp + 16);
    }
    // ---- issue all V loads (independent; latency hides under QK + softmax)
    bf16x8 vf[8];
    #pragma unroll
    for (int t = 0; t < 8; t++)
      vf[t] = load8(V + j0 + t * 16 + hi * 8);
    // ---- QK^T: 8 MFMAs back-to-back
    f32x16 S[4];
    #pragma unroll
    for (int kb = 0; kb < 4; kb++) {
      S[kb] = __builtin_amdgcn_mfma_f32_32x32x16_bf16(kf1[kb], qf1, zero16, 0, 0, 0);
      S[kb] = __builtin_amdgcn_mfma_f32_32x32x16_bf16(kf0[kb], qf0, S[kb], 0, 0, 0);
    }
    // ---- exp2 / tree-sum / pack / LDS write
    #pragma unroll
    for (int kb = 0; kb < 4; kb++) {
      float p[16];
      #pragma unroll
      for (int r = 0; r < 16; r++)
        p[r] = __builtin_amdgcn_exp2f(S[kb][r]);
      float s0 = (p[0] + p[1]) + (p[2] + p[3]);
      float s1 = (p[4] + p[5]) + (p[6] + p[7]);
      float s2 = (p[8] + p[9]) + (p[10] + p[11]);
      float s3 = (p[12] + p[13]) + (p[14] + p[15]);
      psum += (s0 + s1) + (s2 + s3);
      #pragma unroll
      for (int g = 0; g < 4; g++) {
        uint2 dd;
        dd.x = pack_bf2(p[4 * g], p[4 * g + 1]);
        dd.y = pack_bf2(p[4 * g + 2], p[4 * g + 3]);
        // P[query n][key kb*32 + g*8 + 4*hi + {0..3}]
        *(uint2*)(prow + kb * 32 + g * 8 + hi * 4) = dd;
      }
    }
    // ---- PV: O^T[d][q] += V^T[d][k] * P^T[k][q]
    #pragma unroll
    for (int t = 0; t < 8; t++) {
      bf16x8 pf = load8(prow + t * 16 + hi * 8);        // B: n=query, k=keys
      oT = __builtin_amdgcn_mfma_f32_32x32x16_bf16(vf[t], pf, oT, 0, 0, 0);
    }
  }

  // l[query]: lane n holds half the keys, partner lane n^32 the other half
  psum += __shfl_xor(psum, 32, 64);

  // O^T: col=query n, row=d = (reg&3)+8*(reg>>2)+4*hi
  float* pr = po + (((size_t)z * 16 + bh) * HW + (m0 + n)) * 32;
  #pragma unroll
  for (int g = 0; g < 4; g++) {
    f32x4 v4 = (f32x4){oT[4 * g], oT[4 * g + 1], oT[4 * g + 2], oT[4 * g + 3]};
    *(f32x4*)(pr + g * 8 + hi * 4) = v4;
  }
  if (lane < 32)
    pl[((size_t)z * 16 + bh) * HW + m0 + n] = psum;
}

// ---------------- merge partials -> ao_t[b][s][c] bf16
__global__ __launch_bounds__(256) void merge_parts(const float* __restrict__ po,
                                                   const float* __restrict__ pl,
                                                   unsigned short* __restrict__ ao_t) {
  int g = blockIdx.x * 256 + threadIdx.x;   // [0, 16*4096*8)
  int d4 = g & 7, s = (g >> 3) & 4095, bh = g >> 15;
  const float4* p4 = (const float4*)po;
  float4 a = p4[g];
  float4 c = p4[g + (16 * HW * 32 / 4)];
  float l = pl[(size_t)bh * HW + s] + pl[(size_t)(16 + bh) * HW + s];
  float inv = 1.0f / l;
  int b = bh >> 3, h = bh & 7;
  uint2 dd;
  dd.x = pack_bf2((a.x + c.x) * inv, (a.y + c.y) * inv);
  dd.y = pack_bf2((a.z + c.z) * inv, (a.w + c.w) * inv);
  *(uint2*)(ao_t + ((size_t)b * HW + s) * C + h * HD + d4 * 4) = dd;
}

// ---------------- Proj GEMM + bias + residual
__global__ __launch_bounds__(256) void proj_gemm(const unsigned short* __restrict__ wp_b,
                                                 const unsigned short* __restrict__ ao_t,
                                                 const float* __restrict__ b_proj,
                                                 const float* __restrict__ x,
                                                 float* __restrict__ out) {
  int lane = threadIdx.x & 63, w = threadIdx.x >> 6;
  int quad = lane >> 4, l16 = lane & 15;
  int m0 = blockIdx.y * 64 + w * 16;
  int n0 = blockIdx.x * 64;
  int b  = blockIdx.z;
  f32x4 acc[4];
  #pragma unroll
  for (int nb = 0; nb < 4; nb++) acc[nb] = (f32x4){0.f, 0.f, 0.f, 0.f};

  const unsigned short* ab = ao_t + (size_t)b * HW * C;
  for (int k0 = 0; k0 < 256; k0 += 32) {
    bf16x8 a = load8(wp_b + (size_t)(m0 + l16) * 256 + k0 + quad * 8);
    #pragma unroll
    for (int nb = 0; nb < 4; nb++) {
      int s = n0 + nb * 16 + l16;
      bf16x8 bb = load8(ab + (size_t)s * C + k0 + quad * 8);
      acc[nb] = __builtin_amdgcn_mfma_f32_16x16x32_bf16(a, bb, acc[nb], 0, 0, 0);
    }
  }
  #pragma unroll
  for (int nb = 0; nb < 4; nb++) {
    int s = n0 + nb * 16 + l16;
    #pragma unroll
    for (int r = 0; r < 4; r++) {
      int o = m0 + quad * 4 + r;
      size_t idx = ((size_t)b * C + o) * HW + s;
      out[idx] = acc[nb][r] + b_proj[o] + x[idx];
    }
  }
}

extern "C" void kernel_launch(void* const* d_in, const int* in_sizes, int n_in,
                              void* d_out, int out_size, void* d_ws, size_t ws_size,
                              hipStream_t stream) {
  const float* x      = (const float*)d_in[0];
  const float* w_qkv  = (const float*)d_in[1];
  const float* b_qkv  = (const float*)d_in[2];
  const float* w_proj = (const float*)d_in[3];
  const float* b_proj = (const float*)d_in[4];
  const float* gamma  = (const float*)d_in[5];
  const float* beta   = (const float*)d_in[6];
  float* out = (float*)d_out;

  char* ws = (char*)d_ws;
  float*          stats = (float*)ws;                                   // 512 B
  unsigned short* wq_b  = (unsigned short*)(ws + 512);                  // 384 KB
  unsigned short* wp_b  = (unsigned short*)(ws + 512 + 393216);         // 128 KB
  unsigned short* h_t   = (unsigned short*)(ws + 524800);               // 4 MB [b][s][c]
  unsigned short* q_t   = (unsigned short*)(ws + 4719104);              // 4 MB [bh][s][d]
  unsigned short* k_t   = (unsigned short*)(ws + 8913408);              // 4 MB [bh][s][d]
  unsigned short* v_t   = (unsigned short*)(ws + 13107712);             // 4 MB [b][c][s]
  unsigned short* ao_t  = (unsigned short*)(ws + 17302016);             // 4 MB [b][s][c]
  float*          po    = (float*)(ws + 21496320);                      // 16 MB (2 splits)
  float*          pl    = (float*)(ws + 21496320 + 16777216);           // 512 KB

  gn_stats_conv<<<320, 256, 0, stream>>>(x, stats, w_qkv, w_proj, wq_b, wp_b);
  gn_apply<<<dim3(64, 4, 2), 256, 0, stream>>>(x, stats, gamma, beta, h_t);
  qkv_gemm<<<dim3(64, 12, 2), 256, 0, stream>>>(wq_b, h_t, b_qkv, q_t, k_t, v_t);
  flash_part<<<dim3(32, 16, 2), 256, 0, stream>>>(q_t, k_t, v_t, po, pl, HW / 2);
  merge_parts<<<2048, 256, 0, stream>>>(po, pl, ao_t);
  proj_gemm<<<dim3(64, 4, 2), 256, 0, stream>>>(wp_b, ao_t, b_proj, x, out);
}